// Round 3
// baseline (612.691 us; speedup 1.0000x reference)
//
#include <hip/hip_runtime.h>

#define FI4(p) (*(const float4*)(p))

// ---------------------------------------------------------------------------
// Fully-fused L2X model: dense1+dense2+logits GEMMs (LDS-resident
// intermediates) + SampleConcrete + 2-class head. One block = 64 rows,
// 512 threads (8 waves). Phase 2 uses 8-lane groups per row: softmax
// reductions are 3 xor-shuffle steps, per-lane 28-element register loops,
// all global traffic 16B-aligned dwordx4.
// ---------------------------------------------------------------------------
__launch_bounds__(512, 2)
__global__ void l2x_fused(const float* __restrict__ x,
                          const float* __restrict__ uniform,
                          const float* __restrict__ w1, const float* __restrict__ b1,
                          const float* __restrict__ w2, const float* __restrict__ b2,
                          const float* __restrict__ wl, const float* __restrict__ bl,
                          const float* __restrict__ wo, const float* __restrict__ bo,
                          float* __restrict__ out, int B) {
  constexpr int BMP = 68;   // padded row stride for transposed tiles
  constexpr int KC = 20;    // K-chunk (divides 200 and 100)
  constexpr int LGS = 204;  // padded logits row stride
  constexpr float EPS = 1.1920929e-07f;

  __shared__ float At[KC * BMP];      //  5.4 KB: x^T staging chunk [k][r]
  __shared__ float Ws[KC * 256];      // 20.5 KB: weight staging chunk [k][c]
  __shared__ float h1T[100 * BMP];    // 27.2 KB: h1 transposed [k][r]
  __shared__ float h2T[100 * BMP];    // 27.2 KB: h2 transposed [k][r]
  __shared__ float lg[64 * LGS];      // 52.2 KB: logits tile [r][c]
  __shared__ float woS[400];
  __shared__ float boS[2];

  const int t = threadIdx.x;
  const int tx = t & 31, ty = t >> 5;  // 32 col-threads x 16 row-threads
  const int rowBase = blockIdx.x * 64;

  if (t < 400) woS[t] = wo[t];
  if (t < 2) boS[t] = bo[t];

  // ---------------- GEMM 1: h1 = relu(x @ w1 + b1), K=200 N=100 ------------
  {
    float acc[4][4] = {};
    for (int kc = 0; kc < 200; kc += KC) {
      for (int i = t; i < 64 * KC; i += 512) {
        int r = i / KC, k = i - r * KC;
        At[k * BMP + r] = x[(size_t)(rowBase + r) * 200 + kc + k];
      }
      for (int i = t; i < KC * 128; i += 512) {
        int k = i >> 7, c = i & 127;
        Ws[k * 128 + c] = (c < 100) ? w1[(kc + k) * 100 + c] : 0.0f;
      }
      __syncthreads();
#pragma unroll
      for (int k = 0; k < KC; k++) {
        float a[4], bq[4];
        *(float4*)a = FI4(&At[k * BMP + ty * 4]);
        *(float4*)bq = FI4(&Ws[k * 128 + tx * 4]);
#pragma unroll
        for (int i = 0; i < 4; i++)
#pragma unroll
          for (int j = 0; j < 4; j++) acc[i][j] = fmaf(a[i], bq[j], acc[i][j]);
      }
      __syncthreads();
    }
    if (tx < 25) {
      float bv[4];
#pragma unroll
      for (int j = 0; j < 4; j++) bv[j] = b1[tx * 4 + j];
#pragma unroll
      for (int i = 0; i < 4; i++) {
        int r = ty * 4 + i;
#pragma unroll
        for (int j = 0; j < 4; j++)
          h1T[(tx * 4 + j) * BMP + r] = fmaxf(acc[i][j] + bv[j], 0.0f);
      }
    }
  }

  // ---------------- GEMM 2: h2 = relu(h1 @ w2 + b2), K=100 N=100 -----------
  {
    float acc[4][4] = {};
    for (int kc = 0; kc < 100; kc += KC) {
      for (int i = t; i < KC * 128; i += 512) {
        int k = i >> 7, c = i & 127;
        Ws[k * 128 + c] = (c < 100) ? w2[(kc + k) * 100 + c] : 0.0f;
      }
      __syncthreads();
#pragma unroll
      for (int k = 0; k < KC; k++) {
        float a[4], bq[4];
        *(float4*)a = FI4(&h1T[(kc + k) * BMP + ty * 4]);
        *(float4*)bq = FI4(&Ws[k * 128 + tx * 4]);
#pragma unroll
        for (int i = 0; i < 4; i++)
#pragma unroll
          for (int j = 0; j < 4; j++) acc[i][j] = fmaf(a[i], bq[j], acc[i][j]);
      }
      __syncthreads();
    }
    if (tx < 25) {
      float bv[4];
#pragma unroll
      for (int j = 0; j < 4; j++) bv[j] = b2[tx * 4 + j];
#pragma unroll
      for (int i = 0; i < 4; i++) {
        int r = ty * 4 + i;
#pragma unroll
        for (int j = 0; j < 4; j++)
          h2T[(tx * 4 + j) * BMP + r] = fmaxf(acc[i][j] + bv[j], 0.0f);
      }
    }
  }

  // ---------------- GEMM 3: logits = h2 @ wl + bl, K=100 N=200 -------------
  {
    float acc[4][8] = {};
    for (int kc = 0; kc < 100; kc += KC) {
      for (int i = t; i < KC * 256; i += 512) {
        int k = i >> 8, c = i & 255;
        Ws[k * 256 + c] = (c < 200) ? wl[(kc + k) * 200 + c] : 0.0f;
      }
      __syncthreads();
#pragma unroll
      for (int k = 0; k < KC; k++) {
        float a[4], bq[8];
        *(float4*)a = FI4(&h2T[(kc + k) * BMP + ty * 4]);
        *(float4*)&bq[0] = FI4(&Ws[k * 256 + tx * 8]);
        *(float4*)&bq[4] = FI4(&Ws[k * 256 + tx * 8 + 4]);
#pragma unroll
        for (int i = 0; i < 4; i++)
#pragma unroll
          for (int j = 0; j < 8; j++) acc[i][j] = fmaf(a[i], bq[j], acc[i][j]);
      }
      __syncthreads();
    }
    if (tx < 25) {
      float bv[8];
#pragma unroll
      for (int j = 0; j < 8; j++) bv[j] = bl[tx * 8 + j];
#pragma unroll
      for (int i = 0; i < 4; i++) {
        int r = ty * 4 + i;
        float4 v0, v1;
        v0.x = acc[i][0] + bv[0]; v0.y = acc[i][1] + bv[1];
        v0.z = acc[i][2] + bv[2]; v0.w = acc[i][3] + bv[3];
        v1.x = acc[i][4] + bv[4]; v1.y = acc[i][5] + bv[5];
        v1.z = acc[i][6] + bv[6]; v1.w = acc[i][7] + bv[7];
        *(float4*)&lg[r * LGS + tx * 8] = v0;
        *(float4*)&lg[r * LGS + tx * 8 + 4] = v1;
      }
    }
  }
  __syncthreads();

  // ---------------- Phase 2: SampleConcrete + head -------------------------
  // wave = 8 rows; 8-lane group per row; lane owns d = 32*jj + 4*sub + c
  const int lane = t & 63;
  const int wv = t >> 6;
  const int g = lane >> 3, sub = lane & 7;
  const int r = wv * 8 + g;
  const int b = rowBase + r;
  const bool full = (sub < 2);  // slot 6 (d=192..199) validity

  float4 lgv[7], smax[7];
#pragma unroll
  for (int jj = 0; jj < 6; jj++) {
    lgv[jj] = FI4(&lg[r * LGS + jj * 32 + sub * 4]);
    smax[jj] = make_float4(0.f, 0.f, 0.f, 0.f);
  }
  lgv[6] = full ? FI4(&lg[r * LGS + 192 + sub * 4]) : make_float4(0.f, 0.f, 0.f, 0.f);
  smax[6] = make_float4(0.f, 0.f, 0.f, 0.f);

  const float* __restrict__ ub = uniform + (size_t)b * 2000;
  float* smf = (float*)smax;
  const float* lgf = (const float*)lgv;

#pragma unroll
  for (int k = 0; k < 10; k++) {
    float4 u[7];
#pragma unroll
    for (int jj = 0; jj < 6; jj++) u[jj] = FI4(ub + k * 200 + jj * 32 + sub * 4);
    u[6] = full ? FI4(ub + k * 200 + 192 + sub * 4) : make_float4(0.5f, 0.5f, 0.5f, 0.5f);

    float* uf = (float*)u;
    float mloc = -1e30f;
#pragma unroll
    for (int e = 0; e < 28; e++) {
      float uc = fminf(fmaxf(uf[e], EPS), 1.0f);
      float nz = (-__logf(-__logf(uc)) + lgf[e]) * 2.0f;  // / tau0 (=0.5)
      if (e >= 24) nz = full ? nz : -1e30f;
      uf[e] = nz;
      mloc = fmaxf(mloc, nz);
    }
    mloc = fmaxf(mloc, __shfl_xor(mloc, 1));
    mloc = fmaxf(mloc, __shfl_xor(mloc, 2));
    mloc = fmaxf(mloc, __shfl_xor(mloc, 4));

    float ss = 0.0f;
#pragma unroll
    for (int e = 0; e < 28; e++) {
      float ev = __expf(uf[e] - mloc);  // invalid: exp(-huge) -> 0
      uf[e] = ev;
      ss += ev;
    }
    ss += __shfl_xor(ss, 1);
    ss += __shfl_xor(ss, 2);
    ss += __shfl_xor(ss, 4);

    const float inv = 1.0f / ss;
#pragma unroll
    for (int e = 0; e < 28; e++) smf[e] = fmaxf(smf[e], uf[e] * inv);
  }

  // samples out + head partials
  float p0 = 0.0f, p1 = 0.0f;
#pragma unroll
  for (int jj = 0; jj < 7; jj++) {
    if (jj < 6 || full) {
      const int d0 = jj * 32 + sub * 4;
      *(float4*)(out + (size_t)2 * B + (size_t)b * 200 + d0) = smax[jj];
      float4 xv = FI4(x + (size_t)b * 200 + d0);
      float4 wa = FI4(&woS[2 * d0]);
      float4 wb = FI4(&woS[2 * d0 + 4]);
      const float xs0 = xv.x * smax[jj].x, xs1 = xv.y * smax[jj].y;
      const float xs2 = xv.z * smax[jj].z, xs3 = xv.w * smax[jj].w;
      p0 += xs0 * wa.x + xs1 * wa.z + xs2 * wb.x + xs3 * wb.z;
      p1 += xs0 * wa.y + xs1 * wa.w + xs2 * wb.y + xs3 * wb.w;
    }
  }
  p0 += __shfl_xor(p0, 1); p0 += __shfl_xor(p0, 2); p0 += __shfl_xor(p0, 4);
  p1 += __shfl_xor(p1, 1); p1 += __shfl_xor(p1, 2); p1 += __shfl_xor(p1, 4);
  if (sub == 0) {
    const float z0 = p0 + boS[0];
    const float z1 = p1 + boS[1];
    const float m = fmaxf(z0, z1);
    const float e0 = __expf(z0 - m);
    const float e1 = __expf(z1 - m);
    const float s = e0 + e1;
    *(float2*)(out + (size_t)b * 2) = make_float2(e0 / s, e1 / s);
  }
}

extern "C" void kernel_launch(void* const* d_in, const int* in_sizes, int n_in,
                              void* d_out, int out_size, void* d_ws, size_t ws_size,
                              hipStream_t stream) {
  const float* x  = (const float*)d_in[0];
  const float* un = (const float*)d_in[1];
  const float* w1 = (const float*)d_in[2];
  const float* b1 = (const float*)d_in[3];
  const float* w2 = (const float*)d_in[4];
  const float* b2 = (const float*)d_in[5];
  const float* wl = (const float*)d_in[6];
  const float* bl = (const float*)d_in[7];
  const float* wo = (const float*)d_in[8];
  const float* bo = (const float*)d_in[9];
  float* out = (float*)d_out;

  const int B = in_sizes[0] / 200;  // 32768

  l2x_fused<<<B / 64, 512, 0, stream>>>(x, un, w1, b1, w2, b2, wl, bl, wo, bo, out, B);
}